// Round 6
// baseline (267.647 us; speedup 1.0000x reference)
//
#include <hip/hip_runtime.h>

#define NN 32
#define MM 128
#define EE 256
#define DD 128
#define ELB 16   // e's per k_main block

typedef __attribute__((ext_vector_type(8))) short short8;
typedef __attribute__((ext_vector_type(4))) float f32x4;

union U16x8 { uint4 u; short8 s; };

static __device__ __forceinline__ unsigned short f2bf(float f) {
  union { float f; unsigned u; } v; v.f = f;
  unsigned r = v.u + 0x7FFFu + ((v.u >> 16) & 1u);   // RNE
  return (unsigned short)(r >> 16);
}

// ---------------- kernel 1: L = einsum('nd,jd->nj') per i, softmax -> P1 (bf16); P0 = softmax(bkk) ----
__global__ __launch_bounds__(128, 1)
void k_prep(const float* __restrict__ X, const float* __restrict__ Wkk,
            const float* __restrict__ bkk,
            unsigned short* __restrict__ P1g, unsigned short* __restrict__ P0g) {
  const int i  = blockIdx.x;
  const int ty = threadIdx.x >> 6;       // wave = row-frag (n 16-block)
  const int l  = threadIdx.x & 63;
  const int lr = l & 15, lg = l >> 4;

  short8 a[4];
  {
    const int n = ty * 16 + lr;
    const float* xp = X + (n * MM + i) * DD + lg * 8;
#pragma unroll
    for (int k = 0; k < 4; ++k) {
      float4 v0 = *(const float4*)(xp + k * 32);
      float4 v1 = *(const float4*)(xp + k * 32 + 4);
      short8 s;
      s[0]=(short)f2bf(v0.x); s[1]=(short)f2bf(v0.y); s[2]=(short)f2bf(v0.z); s[3]=(short)f2bf(v0.w);
      s[4]=(short)f2bf(v1.x); s[5]=(short)f2bf(v1.y); s[6]=(short)f2bf(v1.z); s[7]=(short)f2bf(v1.w);
      a[k] = s;
    }
  }
  f32x4 acc[8];
#pragma unroll
  for (int cf = 0; cf < 8; ++cf) acc[cf] = (f32x4){0.f, 0.f, 0.f, 0.f};

#pragma unroll
  for (int k = 0; k < 4; ++k) {
#pragma unroll
    for (int cf = 0; cf < 8; ++cf) {
      const int j = cf * 16 + lr;
      const float* wp = Wkk + (i * MM + j) * DD + k * 32 + lg * 8;
      float4 v0 = *(const float4*)(wp);
      float4 v1 = *(const float4*)(wp + 4);
      short8 b;
      b[0]=(short)f2bf(v0.x); b[1]=(short)f2bf(v0.y); b[2]=(short)f2bf(v0.z); b[3]=(short)f2bf(v0.w);
      b[4]=(short)f2bf(v1.x); b[5]=(short)f2bf(v1.y); b[6]=(short)f2bf(v1.z); b[7]=(short)f2bf(v1.w);
      acc[cf] = __builtin_amdgcn_mfma_f32_16x16x32_bf16(a[k], b, acc[cf], 0, 0, 0);
    }
  }

  float bk[8];
#pragma unroll
  for (int cf = 0; cf < 8; ++cf) bk[cf] = bkk[i * MM + cf * 16 + lr];

#pragma unroll
  for (int r = 0; r < 4; ++r) {
    float v[8], m = -1e30f;
#pragma unroll
    for (int cf = 0; cf < 8; ++cf) { v[cf] = acc[cf][r] + bk[cf]; m = fmaxf(m, v[cf]); }
#pragma unroll
    for (int s = 1; s < 16; s <<= 1) m = fmaxf(m, __shfl_xor(m, s, 64));
    float sum = 0.f;
#pragma unroll
    for (int cf = 0; cf < 8; ++cf) { v[cf] = __expf(v[cf] - m); sum += v[cf]; }
#pragma unroll
    for (int s = 1; s < 16; s <<= 1) sum += __shfl_xor(sum, s, 64);
    const float inv = 1.f / sum;
    const int n = ty * 16 + lg * 4 + r;
    unsigned short* dst = P1g + (n * MM + i) * MM;
#pragma unroll
    for (int cf = 0; cf < 8; ++cf) dst[cf * 16 + lr] = f2bf(v[cf] * inv);
  }

  if (ty == 0) {  // P0 row i
    float v0 = bkk[i * MM + l], v1 = bkk[i * MM + 64 + l];
    float m = fmaxf(v0, v1);
#pragma unroll
    for (int s = 1; s < 64; s <<= 1) m = fmaxf(m, __shfl_xor(m, s, 64));
    v0 = __expf(v0 - m); v1 = __expf(v1 - m);
    float sum = v0 + v1;
#pragma unroll
    for (int s = 1; s < 64; s <<= 1) sum += __shfl_xor(sum, s, 64);
    const float inv = 1.f / sum;
    P0g[i * MM + l]      = f2bf(v0 * inv);
    P0g[i * MM + 64 + l] = f2bf(v1 * inv);
  }
}

// ---------------- kernel 1b: per-n aux: XT[n][d][j] = bf16(X[n][j][d])  +  incidence bitmaps ------
__global__ __launch_bounds__(256, 1)
void k_aux(const float* __restrict__ X, const float* __restrict__ inc,
           unsigned short* __restrict__ XTg, unsigned* __restrict__ bmap) {
  __shared__ float xs[128][129];
  const int n = blockIdx.x, t = threadIdx.x;
#pragma unroll
  for (int it = 0; it < 16; ++it) {
    int idx = it * 256 + t;           // 0..4095 float4 tiles
    int j = idx >> 5, dq = idx & 31;
    float4 v = *(const float4*)(X + (n * MM + j) * DD + dq * 4);
    xs[j][dq * 4 + 0] = v.x; xs[j][dq * 4 + 1] = v.y;
    xs[j][dq * 4 + 2] = v.z; xs[j][dq * 4 + 3] = v.w;
  }
  __syncthreads();
  {
    const int d = t >> 1, jh = t & 1;
    unsigned* dst = (unsigned*)XTg + (n * DD + d) * (MM / 2) + jh * 32;
#pragma unroll
    for (int jj = 0; jj < 32; ++jj) {
      int j = jh * 64 + jj * 2;
      unsigned u0 = f2bf(xs[j][d]), u1 = f2bf(xs[j + 1][d]);
      dst[jj] = u0 | (u1 << 16);
    }
  }
  // incidence bitmaps, coalesced over e = t
  {
    const int e = t;
    unsigned bm[4] = {0u, 0u, 0u, 0u};
#pragma unroll
    for (int q = 0; q < 4; ++q)
#pragma unroll 4
      for (int j = 0; j < 32; ++j)
        if (inc[(n * MM + q * 32 + j) * EE + e] != 0.f) bm[q] |= 1u << j;
    uint4 v; v.x = bm[0]; v.y = bm[1]; v.z = bm[2]; v.w = bm[3];
    *(uint4*)(bmap + (n * EE + e) * 4) = v;
  }
}

// ---------------- kernel 2: main. 1024 blocks = 32n x 16eg x 2rh. Computes T^T = XT * P^T. ------
// XT[n] staged in LDS (XOR-swizzled); P rows + w1 frags in registers; MFMA d-reduce epilogue.
__global__ __launch_bounds__(256, 4)
void k_main(const unsigned short* __restrict__ P0g, const unsigned short* __restrict__ P1g,
            const unsigned short* __restrict__ XTg, const unsigned* __restrict__ bmap,
            const float* __restrict__ w1, const float* __restrict__ b1p,
            float* __restrict__ out) {
  __shared__ alignas(128) unsigned short XTlds[128][128];   // 32 KB, XOR-swizzled
  __shared__ unsigned bitm[ELB][4];
  __shared__ alignas(16) unsigned short mrow[ELB][128];     // 4 KB

  const int bid = blockIdx.x;
  const int n = bid & 31, eg = (bid >> 5) & 15, rh = bid >> 9;
  const int t = threadIdx.x, w = t >> 6, l = t & 63, lr = l & 15, lg = l >> 4;
  const int i_lane = rh * 64 + w * 16 + lr;   // this lane's P row / output-col index

  { // stage XT[n] with xor-swizzle ^((row&7)<<4); row = byte>>8 = idx>>4   (verified pair, R2)
    char* d2 = (char*)&XTlds[0][0];
    const uint4* s2 = (const uint4*)(XTg + n * DD * MM);
#pragma unroll
    for (int it = 0; it < 8; ++it) {
      int idx = it * 256 + t;                       // 0..2047 16B chunks
      int off = (idx * 16) ^ (((idx >> 4) & 7) << 4);
      *(uint4*)(d2 + off) = s2[idx];
    }
  }
  if (t < ELB)
    *(uint4*)&bitm[t][0] = *(const uint4*)(bmap + (n * EE + eg * ELB + t) * 4);

  // P fragments (B-operands): row i_lane, k-slices
  uint4 p0[4], p1[4];
  {
    const unsigned short* pb0 = P0g + i_lane * MM;
    const unsigned short* pb1 = P1g + n * MM * MM + i_lane * MM;
#pragma unroll
    for (int k = 0; k < 4; ++k) {
      p0[k] = *(const uint4*)(pb0 + k * 32 + lg * 8);
      p1[k] = *(const uint4*)(pb1 + k * 32 + lg * 8);
    }
  }
  // w1 B-fragments, packed per cf-pair to match the custom K=32 epilogue contraction
  short8 w1pk[4];
#pragma unroll
  for (int p = 0; p < 4; ++p) {
    float4 a = *(const float4*)(w1 + (2 * p) * 16 + lg * 4);
    float4 b = *(const float4*)(w1 + (2 * p + 1) * 16 + lg * 4);
    short8 s;
    s[0]=(short)f2bf(a.x); s[1]=(short)f2bf(a.y); s[2]=(short)f2bf(a.z); s[3]=(short)f2bf(a.w);
    s[4]=(short)f2bf(b.x); s[5]=(short)f2bf(b.y); s[6]=(short)f2bf(b.z); s[7]=(short)f2bf(b.w);
    w1pk[p] = s;
  }
  const float b1v = b1p[0];
  const int selsh = (w & 1) * 16 + lr;
  const int selwd = rh * 2 + (w >> 1);
  __syncthreads();

  if (t < ELB * 8) {  // expand bitmap -> u16 AND-masks over contracted dim j
    int el = t >> 3, j0 = (t & 7) * 16;
    unsigned wd = bitm[el][j0 >> 5];
    int sh = j0 & 31;
    unsigned short* mp = &mrow[el][j0];
#pragma unroll
    for (int b = 0; b < 16; ++b) mp[b] = ((wd >> (sh + b)) & 1u) ? 0xFFFFu : 0u;
  }
  __syncthreads();

  // A-read: off = (row*256 + k*64 + lg*16) ^ ((row&7)<<4), row = cf*16+lr.
  // row*256 lives in bits>=8; XOR field is bits 4..7 -> keep the XOR inside (k*64+lg*16).
  const char* xbase = (const char*)&XTlds[0][0] + lr * 256;
  const int xmask = (lr & 7) << 4;
  float* outp = out + (n * EE + eg * ELB) * MM + rh * 64 + w * 16 + lg * 4;

#pragma unroll 1
  for (int el = 0; el < ELB; ++el) {
    const unsigned selw = bitm[el][selwd];
    const bool sel = ((selw >> selsh) & 1u) != 0u;
    f32x4 acc[8];
#pragma unroll
    for (int cf = 0; cf < 8; ++cf) acc[cf] = (f32x4){0.f, 0.f, 0.f, 0.f};

#pragma unroll
    for (int k = 0; k < 4; ++k) {
      uint4 mm = *(const uint4*)((const char*)&mrow[el][0] + k * 64 + lg * 16);
      U16x8 pvv;
      pvv.u.x = (sel ? p1[k].x : p0[k].x) & mm.x;
      pvv.u.y = (sel ? p1[k].y : p0[k].y) & mm.y;
      pvv.u.z = (sel ? p1[k].z : p0[k].z) & mm.z;
      pvv.u.w = (sel ? p1[k].w : p0[k].w) & mm.w;
      const int xko = (k * 64 + lg * 16) ^ xmask;
#pragma unroll
      for (int cf = 0; cf < 8; ++cf) {
        U16x8 xv; xv.u = *(const uint4*)(xbase + cf * 4096 + xko);
        acc[cf] = __builtin_amdgcn_mfma_f32_16x16x32_bf16(xv.s, pvv.s, acc[cf], 0, 0, 0);
      }
    }

    // epilogue: relu -> bf16, reduce over d with 2 independent MFMA chains, no cross-lane ops
    f32x4 acc3a = (f32x4){b1v, b1v, b1v, b1v};
    f32x4 acc3b = (f32x4){0.f, 0.f, 0.f, 0.f};
#pragma unroll
    for (int p = 0; p < 4; ++p) {
      float a0 = fmaxf(acc[2*p][0], 0.f), a1 = fmaxf(acc[2*p][1], 0.f);
      float a2 = fmaxf(acc[2*p][2], 0.f), a3 = fmaxf(acc[2*p][3], 0.f);
      float c0 = fmaxf(acc[2*p+1][0], 0.f), c1 = fmaxf(acc[2*p+1][1], 0.f);
      float c2 = fmaxf(acc[2*p+1][2], 0.f), c3 = fmaxf(acc[2*p+1][3], 0.f);
      unsigned u0, u1, u2, u3;
      asm("v_cvt_pk_bf16_f32 %0, %1, %2" : "=v"(u0) : "v"(a0), "v"(a1));
      asm("v_cvt_pk_bf16_f32 %0, %1, %2" : "=v"(u1) : "v"(a2), "v"(a3));
      asm("v_cvt_pk_bf16_f32 %0, %1, %2" : "=v"(u2) : "v"(c0), "v"(c1));
      asm("v_cvt_pk_bf16_f32 %0, %1, %2" : "=v"(u3) : "v"(c2), "v"(c3));
      U16x8 uu; uu.u.x = u0; uu.u.y = u1; uu.u.z = u2; uu.u.w = u3;
      if (p & 1)
        acc3b = __builtin_amdgcn_mfma_f32_16x16x32_bf16(uu.s, w1pk[p], acc3b, 0, 0, 0);
      else
        acc3a = __builtin_amdgcn_mfma_f32_16x16x32_bf16(uu.s, w1pk[p], acc3a, 0, 0, 0);
    }
    acc3a[0] += acc3b[0]; acc3a[1] += acc3b[1];
    acc3a[2] += acc3b[2]; acc3a[3] += acc3b[3];

    if (lr == 0) *(float4*)(outp + el * MM) = *(float4*)&acc3a;
  }
}

extern "C" void kernel_launch(void* const* d_in, const int* in_sizes, int n_in,
                              void* d_out, int out_size, void* d_ws, size_t ws_size,
                              hipStream_t stream) {
  const float* X   = (const float*)d_in[0];
  const float* inc = (const float*)d_in[1];
  const float* Wkk = (const float*)d_in[2];
  const float* bkk = (const float*)d_in[3];
  const float* w1  = (const float*)d_in[4];
  const float* b1  = (const float*)d_in[5];
  float* out = (float*)d_out;

  unsigned short* P1g = (unsigned short*)d_ws;          // 32*128*128 u16 = 1 MB
  unsigned short* XTg = P1g + NN * MM * DD;             // 1 MB
  unsigned short* P0g = XTg + NN * MM * DD;             // 32 KB
  unsigned* bmap = (unsigned*)(P0g + MM * MM);          // 32*256*4 u32 = 128 KB

  hipLaunchKernelGGL(k_prep, dim3(128), dim3(128), 0, stream, X, Wkk, bkk, P1g, P0g);
  hipLaunchKernelGGL(k_aux,  dim3(32),  dim3(256), 0, stream, X, inc, XTg, bmap);
  hipLaunchKernelGGL(k_main, dim3(1024), dim3(256), 0, stream, P0g, P1g, XTg, bmap, w1, b1, out);
}

// Round 7
// 56.867 us; speedup vs baseline: 4.7065x; 4.7065x over previous
//
#include <hip/hip_runtime.h>

#define NN 32
#define MM 128
#define EE 256
#define DD 128
#define ELB 16   // e's per k_main block

typedef __attribute__((ext_vector_type(8))) short short8;
typedef __attribute__((ext_vector_type(4))) float f32x4;

union U16x8 { uint4 u; short8 s; };

static __device__ __forceinline__ unsigned short f2bf(float f) {
  union { float f; unsigned u; } v; v.f = f;
  unsigned r = v.u + 0x7FFFu + ((v.u >> 16) & 1u);   // RNE
  return (unsigned short)(r >> 16);
}

// ---------------- kernel 1: L = einsum('nd,jd->nj') per i, softmax -> P1 (bf16); P0 = softmax(bkk) ----
__global__ __launch_bounds__(128, 1)
void k_prep(const float* __restrict__ X, const float* __restrict__ Wkk,
            const float* __restrict__ bkk,
            unsigned short* __restrict__ P1g, unsigned short* __restrict__ P0g) {
  const int i  = blockIdx.x;
  const int ty = threadIdx.x >> 6;       // wave = row-frag (n 16-block)
  const int l  = threadIdx.x & 63;
  const int lr = l & 15, lg = l >> 4;

  short8 a[4];
  {
    const int n = ty * 16 + lr;
    const float* xp = X + (n * MM + i) * DD + lg * 8;
#pragma unroll
    for (int k = 0; k < 4; ++k) {
      float4 v0 = *(const float4*)(xp + k * 32);
      float4 v1 = *(const float4*)(xp + k * 32 + 4);
      short8 s;
      s[0]=(short)f2bf(v0.x); s[1]=(short)f2bf(v0.y); s[2]=(short)f2bf(v0.z); s[3]=(short)f2bf(v0.w);
      s[4]=(short)f2bf(v1.x); s[5]=(short)f2bf(v1.y); s[6]=(short)f2bf(v1.z); s[7]=(short)f2bf(v1.w);
      a[k] = s;
    }
  }
  f32x4 acc[8];
#pragma unroll
  for (int cf = 0; cf < 8; ++cf) acc[cf] = (f32x4){0.f, 0.f, 0.f, 0.f};

#pragma unroll
  for (int k = 0; k < 4; ++k) {
#pragma unroll
    for (int cf = 0; cf < 8; ++cf) {
      const int j = cf * 16 + lr;
      const float* wp = Wkk + (i * MM + j) * DD + k * 32 + lg * 8;
      float4 v0 = *(const float4*)(wp);
      float4 v1 = *(const float4*)(wp + 4);
      short8 b;
      b[0]=(short)f2bf(v0.x); b[1]=(short)f2bf(v0.y); b[2]=(short)f2bf(v0.z); b[3]=(short)f2bf(v0.w);
      b[4]=(short)f2bf(v1.x); b[5]=(short)f2bf(v1.y); b[6]=(short)f2bf(v1.z); b[7]=(short)f2bf(v1.w);
      acc[cf] = __builtin_amdgcn_mfma_f32_16x16x32_bf16(a[k], b, acc[cf], 0, 0, 0);
    }
  }

  float bk[8];
#pragma unroll
  for (int cf = 0; cf < 8; ++cf) bk[cf] = bkk[i * MM + cf * 16 + lr];

#pragma unroll
  for (int r = 0; r < 4; ++r) {
    float v[8], m = -1e30f;
#pragma unroll
    for (int cf = 0; cf < 8; ++cf) { v[cf] = acc[cf][r] + bk[cf]; m = fmaxf(m, v[cf]); }
#pragma unroll
    for (int s = 1; s < 16; s <<= 1) m = fmaxf(m, __shfl_xor(m, s, 64));
    float sum = 0.f;
#pragma unroll
    for (int cf = 0; cf < 8; ++cf) { v[cf] = __expf(v[cf] - m); sum += v[cf]; }
#pragma unroll
    for (int s = 1; s < 16; s <<= 1) sum += __shfl_xor(sum, s, 64);
    const float inv = 1.f / sum;
    const int n = ty * 16 + lg * 4 + r;
    unsigned short* dst = P1g + (n * MM + i) * MM;
#pragma unroll
    for (int cf = 0; cf < 8; ++cf) dst[cf * 16 + lr] = f2bf(v[cf] * inv);
  }

  if (ty == 0) {  // P0 row i
    float v0 = bkk[i * MM + l], v1 = bkk[i * MM + 64 + l];
    float m = fmaxf(v0, v1);
#pragma unroll
    for (int s = 1; s < 64; s <<= 1) m = fmaxf(m, __shfl_xor(m, s, 64));
    v0 = __expf(v0 - m); v1 = __expf(v1 - m);
    float sum = v0 + v1;
#pragma unroll
    for (int s = 1; s < 64; s <<= 1) sum += __shfl_xor(sum, s, 64);
    const float inv = 1.f / sum;
    P0g[i * MM + l]      = f2bf(v0 * inv);
    P0g[i * MM + 64 + l] = f2bf(v1 * inv);
  }
}

// ---------------- kernel 1b: per-n aux: XT[n][d][j] = bf16(X[n][j][d])  +  incidence bitmaps ------
__global__ __launch_bounds__(256, 1)
void k_aux(const float* __restrict__ X, const float* __restrict__ inc,
           unsigned short* __restrict__ XTg, unsigned* __restrict__ bmap) {
  __shared__ float xs[128][129];
  const int n = blockIdx.x, t = threadIdx.x;
#pragma unroll
  for (int it = 0; it < 16; ++it) {
    int idx = it * 256 + t;           // 0..4095 float4 tiles
    int j = idx >> 5, dq = idx & 31;
    float4 v = *(const float4*)(X + (n * MM + j) * DD + dq * 4);
    xs[j][dq * 4 + 0] = v.x; xs[j][dq * 4 + 1] = v.y;
    xs[j][dq * 4 + 2] = v.z; xs[j][dq * 4 + 3] = v.w;
  }
  __syncthreads();
  {
    const int d = t >> 1, jh = t & 1;
    unsigned* dst = (unsigned*)XTg + (n * DD + d) * (MM / 2) + jh * 32;
#pragma unroll
    for (int jj = 0; jj < 32; ++jj) {
      int j = jh * 64 + jj * 2;
      unsigned u0 = f2bf(xs[j][d]), u1 = f2bf(xs[j + 1][d]);
      dst[jj] = u0 | (u1 << 16);
    }
  }
  // incidence bitmaps, coalesced over e = t
  {
    const int e = t;
    unsigned bm[4] = {0u, 0u, 0u, 0u};
#pragma unroll
    for (int q = 0; q < 4; ++q)
#pragma unroll 4
      for (int j = 0; j < 32; ++j)
        if (inc[(n * MM + q * 32 + j) * EE + e] != 0.f) bm[q] |= 1u << j;
    uint4 v; v.x = bm[0]; v.y = bm[1]; v.z = bm[2]; v.w = bm[3];
    *(uint4*)(bmap + (n * EE + e) * 4) = v;
  }
}

// ---------------- kernel 2: main. 1024 blocks = 32n x 16eg x 2rh. Computes T^T = XT * P^T. ------
// XT[n] staged in LDS (XOR-swizzled); P rows + w1 frags pinned in registers; MFMA d-reduce epilogue.
__global__ __launch_bounds__(256, 2)
void k_main(const unsigned short* __restrict__ P0g, const unsigned short* __restrict__ P1g,
            const unsigned short* __restrict__ XTg, const unsigned* __restrict__ bmap,
            const float* __restrict__ w1, const float* __restrict__ b1p,
            float* __restrict__ out) {
  __shared__ alignas(128) unsigned short XTlds[128][128];   // 32 KB, XOR-swizzled
  __shared__ unsigned bitm[ELB][4];
  __shared__ alignas(16) unsigned short mrow[ELB][128];     // 4 KB

  const int bid = blockIdx.x;
  const int n = bid & 31, eg = (bid >> 5) & 15, rh = bid >> 9;
  const int t = threadIdx.x, w = t >> 6, l = t & 63, lr = l & 15, lg = l >> 4;
  const int i_lane = rh * 64 + w * 16 + lr;   // this lane's P row / output-col index

  { // stage XT[n] with xor-swizzle ^((row&7)<<4); row = byte>>8 = idx>>4   (verified pair, R2)
    char* d2 = (char*)&XTlds[0][0];
    const uint4* s2 = (const uint4*)(XTg + n * DD * MM);
#pragma unroll
    for (int it = 0; it < 8; ++it) {
      int idx = it * 256 + t;                       // 0..2047 16B chunks
      int off = (idx * 16) ^ (((idx >> 4) & 7) << 4);
      *(uint4*)(d2 + off) = s2[idx];
    }
  }
  if (t < ELB)
    *(uint4*)&bitm[t][0] = *(const uint4*)(bmap + (n * EE + eg * ELB + t) * 4);

  // P fragments (B-operands): row i_lane, k-slices  -- loaded ONCE, pinned below
  uint4 p0[4], p1[4];
  {
    const unsigned short* pb0 = P0g + i_lane * MM;
    const unsigned short* pb1 = P1g + n * MM * MM + i_lane * MM;
#pragma unroll
    for (int k = 0; k < 4; ++k) {
      p0[k] = *(const uint4*)(pb0 + k * 32 + lg * 8);
      p1[k] = *(const uint4*)(pb1 + k * 32 + lg * 8);
    }
  }
  // w1 B-fragments, packed per cf-pair to match the custom K=32 epilogue contraction
  U16x8 w1u[4];
#pragma unroll
  for (int p = 0; p < 4; ++p) {
    float4 a = *(const float4*)(w1 + (2 * p) * 16 + lg * 4);
    float4 b = *(const float4*)(w1 + (2 * p + 1) * 16 + lg * 4);
    short8 s;
    s[0]=(short)f2bf(a.x); s[1]=(short)f2bf(a.y); s[2]=(short)f2bf(a.z); s[3]=(short)f2bf(a.w);
    s[4]=(short)f2bf(b.x); s[5]=(short)f2bf(b.y); s[6]=(short)f2bf(b.z); s[7]=(short)f2bf(b.w);
    w1u[p].s = s;
  }
  // PIN loop-invariants in registers: read-write asm makes sinking/remat illegal.
#pragma unroll
  for (int k = 0; k < 4; ++k) {
    asm volatile("" : "+v"(p0[k].x), "+v"(p0[k].y), "+v"(p0[k].z), "+v"(p0[k].w));
    asm volatile("" : "+v"(p1[k].x), "+v"(p1[k].y), "+v"(p1[k].z), "+v"(p1[k].w));
    asm volatile("" : "+v"(w1u[k].u.x), "+v"(w1u[k].u.y), "+v"(w1u[k].u.z), "+v"(w1u[k].u.w));
  }
  const float b1v = b1p[0];
  const int selsh = (w & 1) * 16 + lr;
  const int selwd = rh * 2 + (w >> 1);
  __syncthreads();

  if (t < ELB * 8) {  // expand bitmap -> u16 AND-masks over contracted dim j
    int el = t >> 3, j0 = (t & 7) * 16;
    unsigned wd = bitm[el][j0 >> 5];
    int sh = j0 & 31;
    unsigned short* mp = &mrow[el][j0];
#pragma unroll
    for (int b = 0; b < 16; ++b) mp[b] = ((wd >> (sh + b)) & 1u) ? 0xFFFFu : 0u;
  }
  __syncthreads();

  // A-read: off = (row*256 + k*64 + lg*16) ^ ((row&7)<<4), row = cf*16+lr.
  // row*256 lives in bits>=8; XOR field is bits 4..7 -> keep the XOR inside (k*64+lg*16).
  const char* xbase = (const char*)&XTlds[0][0] + lr * 256;
  const int xmask = (lr & 7) << 4;
  float* outp = out + (n * EE + eg * ELB) * MM + rh * 64 + w * 16 + lg * 4;

#pragma unroll 1
  for (int el = 0; el < ELB; ++el) {
    const unsigned selw = bitm[el][selwd];
    const bool sel = ((selw >> selsh) & 1u) != 0u;
    f32x4 acc[8];
#pragma unroll
    for (int cf = 0; cf < 8; ++cf) acc[cf] = (f32x4){0.f, 0.f, 0.f, 0.f};

#pragma unroll
    for (int k = 0; k < 4; ++k) {
      uint4 mm = *(const uint4*)((const char*)&mrow[el][0] + k * 64 + lg * 16);
      U16x8 pvv;
      pvv.u.x = (sel ? p1[k].x : p0[k].x) & mm.x;
      pvv.u.y = (sel ? p1[k].y : p0[k].y) & mm.y;
      pvv.u.z = (sel ? p1[k].z : p0[k].z) & mm.z;
      pvv.u.w = (sel ? p1[k].w : p0[k].w) & mm.w;
      const int xko = (k * 64 + lg * 16) ^ xmask;
#pragma unroll
      for (int cf = 0; cf < 8; ++cf) {
        U16x8 xv; xv.u = *(const uint4*)(xbase + cf * 4096 + xko);
        acc[cf] = __builtin_amdgcn_mfma_f32_16x16x32_bf16(xv.s, pvv.s, acc[cf], 0, 0, 0);
      }
    }

    // epilogue: relu -> bf16, reduce over d with 2 independent MFMA chains, no cross-lane ops
    f32x4 acc3a = (f32x4){b1v, b1v, b1v, b1v};
    f32x4 acc3b = (f32x4){0.f, 0.f, 0.f, 0.f};
#pragma unroll
    for (int p = 0; p < 4; ++p) {
      float a0 = fmaxf(acc[2*p][0], 0.f), a1 = fmaxf(acc[2*p][1], 0.f);
      float a2 = fmaxf(acc[2*p][2], 0.f), a3 = fmaxf(acc[2*p][3], 0.f);
      float c0 = fmaxf(acc[2*p+1][0], 0.f), c1 = fmaxf(acc[2*p+1][1], 0.f);
      float c2 = fmaxf(acc[2*p+1][2], 0.f), c3 = fmaxf(acc[2*p+1][3], 0.f);
      unsigned u0, u1, u2, u3;
      asm("v_cvt_pk_bf16_f32 %0, %1, %2" : "=v"(u0) : "v"(a0), "v"(a1));
      asm("v_cvt_pk_bf16_f32 %0, %1, %2" : "=v"(u1) : "v"(a2), "v"(a3));
      asm("v_cvt_pk_bf16_f32 %0, %1, %2" : "=v"(u2) : "v"(c0), "v"(c1));
      asm("v_cvt_pk_bf16_f32 %0, %1, %2" : "=v"(u3) : "v"(c2), "v"(c3));
      U16x8 uu; uu.u.x = u0; uu.u.y = u1; uu.u.z = u2; uu.u.w = u3;
      if (p & 1)
        acc3b = __builtin_amdgcn_mfma_f32_16x16x32_bf16(uu.s, w1u[p].s, acc3b, 0, 0, 0);
      else
        acc3a = __builtin_amdgcn_mfma_f32_16x16x32_bf16(uu.s, w1u[p].s, acc3a, 0, 0, 0);
    }
    acc3a[0] += acc3b[0]; acc3a[1] += acc3b[1];
    acc3a[2] += acc3b[2]; acc3a[3] += acc3b[3];

    if (lr == 0) *(float4*)(outp + el * MM) = *(float4*)&acc3a;
  }
}

extern "C" void kernel_launch(void* const* d_in, const int* in_sizes, int n_in,
                              void* d_out, int out_size, void* d_ws, size_t ws_size,
                              hipStream_t stream) {
  const float* X   = (const float*)d_in[0];
  const float* inc = (const float*)d_in[1];
  const float* Wkk = (const float*)d_in[2];
  const float* bkk = (const float*)d_in[3];
  const float* w1  = (const float*)d_in[4];
  const float* b1  = (const float*)d_in[5];
  float* out = (float*)d_out;

  unsigned short* P1g = (unsigned short*)d_ws;          // 32*128*128 u16 = 1 MB
  unsigned short* XTg = P1g + NN * MM * DD;             // 1 MB
  unsigned short* P0g = XTg + NN * MM * DD;             // 32 KB
  unsigned* bmap = (unsigned*)(P0g + MM * MM);          // 32*256*4 u32 = 128 KB

  hipLaunchKernelGGL(k_prep, dim3(128), dim3(128), 0, stream, X, Wkk, bkk, P1g, P0g);
  hipLaunchKernelGGL(k_aux,  dim3(32),  dim3(256), 0, stream, X, inc, XTg, bmap);
  hipLaunchKernelGGL(k_main, dim3(1024), dim3(256), 0, stream, P0g, P1g, XTg, bmap, w1, b1, out);
}